// Round 2
// baseline (431.225 us; speedup 1.0000x reference)
//
#include <hip/hip_runtime.h>
#include <hip/hip_bf16.h>
#include <cstdint>
#include <cstddef>

typedef __bf16 bf16_t;
typedef __bf16 bf8_t __attribute__((ext_vector_type(8)));
typedef float f4_t __attribute__((ext_vector_type(4)));
typedef float f8_t __attribute__((ext_vector_type(8)));

#define DEV static __device__ __forceinline__

DEV f4_t mfma16(bf8_t a, bf8_t b, f4_t c) {
    return __builtin_amdgcn_mfma_f32_16x16x32_bf16(a, b, c, 0, 0, 0);
}

DEV bf8_t cvt8(f8_t v) {
    bf8_t r;
#pragma unroll
    for (int i = 0; i < 8; ++i) r[i] = (bf16_t)v[i];
    return r;
}

DEV void load_lds16(const bf16_t* g, bf16_t* l) {
    __builtin_amdgcn_global_load_lds(
        (const __attribute__((address_space(1))) uint32_t*)g,
        (__attribute__((address_space(3))) uint32_t*)l,
        16, 0, 0);
}

// Fused fp32->bf16 convert for x + wq + wk + wv in one launch.
__global__ __launch_bounds__(256) void cvt_fused(const float* __restrict__ x,
                                                 const float* __restrict__ wq,
                                                 const float* __restrict__ wk,
                                                 const float* __restrict__ wv,
                                                 bf16_t* __restrict__ xb,
                                                 bf16_t* __restrict__ wqkvb) {
    const int bid = blockIdx.x;
    const float* src;
    bf16_t* dst;
    int base;
    if (bid < 4096) {
        src = x; dst = xb; base = bid;
    } else {
        const int seg = (bid - 4096) >> 11; // 0,1,2
        src = (seg == 0) ? wq : (seg == 1) ? wk : wv;
        dst = wqkvb + (size_t)seg * 4194304;
        base = (bid - 4096) & 2047;
    }
    const size_t i = ((size_t)base * 256 + threadIdx.x) * 8;
    const f8_t v = *(const f8_t*)&src[i];
    *(bf8_t*)&dst[i] = cvt8(v);
}

__global__ __launch_bounds__(256) void cvt_bf16(const float* __restrict__ in,
                                                bf16_t* __restrict__ out, int n8) {
    const int i = blockIdx.x * 256 + threadIdx.x;
    if (i < n8) {
        const f8_t v = *(const f8_t*)&in[(size_t)i * 8];
        *(bf8_t*)&out[(size_t)i * 8] = cvt8(v);
    }
}

// m97 GEMM + XOR-swizzled LDS (bank-conflict-free b128 frag reads).
// Staging: lane (srow=lane>>2, c=lane&3) fetches global 16B chunk (c ^ ((srow>>1)&3));
// frag reads XOR q4 with ((r16>>1)&3).
// MODE 0 (QKV): Q/K via LDS repack -> 16B stores; V transposed to Vt [B*H][128][S].
// MODE 1: fp32 C [M,2048].
template <int MODE>
__global__ __launch_bounds__(256) void gemm_m97(const bf16_t* __restrict__ A,
                                                const bf16_t* __restrict__ B,
                                                void* __restrict__ C0,
                                                bf16_t* __restrict__ C1,
                                                bf16_t* __restrict__ C2,
                                                int N, int K) {
    constexpr int SMEMN = (MODE == 0) ? 128 * 136 : 8192;
    __shared__ bf16_t smem[SMEMN];
    bf16_t* As = smem;
    bf16_t* Bs = smem + 4096;

    const int tid = threadIdx.x;
    const int lane = tid & 63;
    const int wave = tid >> 6;
    const int bm0 = blockIdx.y * 128;
    const int bn0 = blockIdx.x * 128;
    const int wm = (wave >> 1) * 64;
    const int wn = (wave & 1) * 64;
    const int q4 = lane >> 4;
    const int r16 = lane & 15;

    const int srow = lane >> 2;
    const int scol = (((lane & 3) ^ ((lane >> 3) & 3))) * 8; // swizzled 16B chunk
    const int rkey = (r16 >> 1) & 3;                         // read-side XOR key

    f4_t acc[4][4] = {};

    for (int k0 = 0; k0 < K; k0 += 32) {
        __syncthreads();
        load_lds16(A + (size_t)(bm0 + wave * 16 + srow) * K + k0 + scol, As + wave * 16 * 32);
        load_lds16(A + (size_t)(bm0 + 64 + wave * 16 + srow) * K + k0 + scol,
                   As + (64 + wave * 16) * 32);
        load_lds16(B + (size_t)(bn0 + wave * 16 + srow) * K + k0 + scol, Bs + wave * 16 * 32);
        load_lds16(B + (size_t)(bn0 + 64 + wave * 16 + srow) * K + k0 + scol,
                   Bs + (64 + wave * 16) * 32);
        __syncthreads();

        bf8_t af[4], bfr[4];
#pragma unroll
        for (int i = 0; i < 4; ++i)
            af[i] = *(const bf8_t*)&As[(wm + i * 16 + r16) * 32 + (q4 ^ rkey) * 8];
#pragma unroll
        for (int j = 0; j < 4; ++j)
            bfr[j] = *(const bf8_t*)&Bs[(wn + j * 16 + r16) * 32 + (q4 ^ rkey) * 8];
#pragma unroll
        for (int i = 0; i < 4; ++i)
#pragma unroll
            for (int j = 0; j < 4; ++j)
                acc[i][j] = mfma16(af[i], bfr[j], acc[i][j]);
    }

    if (MODE == 1) {
        float* C = (float*)C0;
#pragma unroll
        for (int i = 0; i < 4; ++i)
#pragma unroll
            for (int j = 0; j < 4; ++j)
#pragma unroll
                for (int r = 0; r < 4; ++r) {
                    const int m = bm0 + wm + i * 16 + q4 * 4 + r;
                    const int n = bn0 + wn + j * 16 + r16;
                    C[(size_t)m * 2048 + n] = acc[i][j][r];
                }
        return;
    }

    __syncthreads(); // K-loop LDS reads done; smem reusable for epilogue repack
    if (bn0 < 4096) {
        // Q/K: repack [m][n] in LDS, then coalesced 16B row stores
        bf16_t* dst = (bn0 < 2048) ? (bf16_t*)C0 : C1;
        const int nbase = bn0 & 2047;
#pragma unroll
        for (int i = 0; i < 4; ++i)
#pragma unroll
            for (int j = 0; j < 4; ++j)
#pragma unroll
                for (int r = 0; r < 4; ++r)
                    smem[(wm + i * 16 + q4 * 4 + r) * 136 + wn + j * 16 + r16] =
                        (bf16_t)acc[i][j][r];
        __syncthreads();
#pragma unroll
        for (int it = 0; it < 8; ++it) {
            const int idx = it * 256 + tid;
            const int m = idx >> 4;
            const int nc = (idx & 15) * 8;
            *(bf8_t*)&dst[(size_t)(bm0 + m) * 2048 + nbase + nc] =
                *(const bf8_t*)&smem[m * 136 + nc];
        }
    } else {
        // V: transpose in LDS, coalesced 16B stores to Vt [bh][d][s]
#pragma unroll
        for (int i = 0; i < 4; ++i)
#pragma unroll
            for (int j = 0; j < 4; ++j)
#pragma unroll
                for (int r = 0; r < 4; ++r)
                    smem[(wn + j * 16 + r16) * 136 + wm + i * 16 + q4 * 4 + r] =
                        (bf16_t)acc[i][j][r];
        __syncthreads();
        const int bb = bm0 >> 11;
        const int s0 = bm0 & 2047;
        const int nh0 = bn0 - 4096;
#pragma unroll
        for (int it = 0; it < 8; ++it) {
            const int idx = it * 256 + tid;
            const int n = idx >> 4;
            const int mc = (idx & 15) * 8;
            const bf8_t v = *(const bf8_t*)&smem[n * 136 + mc];
            const int dg = nh0 + n;
            const int h = dg >> 7, d = dg & 127;
            *(bf8_t*)&C2[(((size_t)(bb * 16 + h) * 128 + d) << 11) + s0 + mc] = v;
        }
    }
}

// Flash v5: 4 waves x 32 q rows (two 16-row strips/wave) -> each K/V fragment read
// feeds 2 MFMAs; swizzled K/V LDS; shuffle-free softmax (no max, ones-MFMA row sums).
__global__ __launch_bounds__(256) void flash5(const bf16_t* __restrict__ Q,
                                              const bf16_t* __restrict__ K,
                                              const bf16_t* __restrict__ VT,
                                              bf16_t* __restrict__ O) {
    constexpr int S = 2048, C = 2048;
    constexpr float SCL = 0.08838834764831845f * 1.4426950408889634f; // 1/sqrt(128)*log2(e)
    __shared__ bf16_t Ks[4 * 64 * 32];  // 4 d-chunks [64 kv][32 d], swizzled
    __shared__ bf16_t Vs[2 * 128 * 32]; // 2 kv-chunks [128 d][32 kv], swizzled
    __shared__ bf16_t Ps[4][32 * 72];   // per-wave P strip (32 q rows)

    const int tid = threadIdx.x, lane = tid & 63, wave = tid >> 6;
    const int q4 = lane >> 4, r16 = lane & 15;
    const int bh = blockIdx.y, b = bh >> 4, h = bh & 15;
    const int q0 = blockIdx.x * 128 + wave * 32;

    const size_t qrow = (size_t)b * S + q0;
    const bf16_t* Qp0 = Q + (qrow + r16) * C + h * 128;
    const bf16_t* Qp1 = Q + (qrow + 16 + r16) * C + h * 128;
    const bf16_t* Kbase = K + (size_t)b * S * C + h * 128;
    const bf16_t* Vbase = VT + (size_t)bh * 128 * S;
    bf16_t* Pw = &Ps[wave][0];

    const int srow = lane >> 2;
    const int scol = (((lane & 3) ^ ((lane >> 3) & 3))) * 8;
    const int rkey = (r16 >> 1) & 3;

    bf8_t aq0[4], aq1[4];
#pragma unroll
    for (int kk = 0; kk < 4; ++kk) {
        aq0[kk] = *(const bf8_t*)&Qp0[kk * 32 + q4 * 8];
        aq1[kk] = *(const bf8_t*)&Qp1[kk * 32 + q4 * 8];
    }

    bf8_t ones;
#pragma unroll
    for (int i = 0; i < 8; ++i) ones[i] = (bf16_t)1.0f;

    f4_t o0[8] = {}, o1[8] = {};
    f4_t lacc0 = {}, lacc1 = {};

    for (int kv0 = 0; kv0 < S; kv0 += 64) {
        __syncthreads(); // prev-iter LDS reads done
        // K: wave w stages d-chunk w (4 DMAs x 16 rows x 64B)
#pragma unroll
        for (int r0 = 0; r0 < 64; r0 += 16)
            load_lds16(Kbase + (size_t)(kv0 + r0 + srow) * C + wave * 32 + scol,
                       Ks + wave * 2048 + r0 * 32);
        // V: wave w stages kv-chunk (w>>1), d-row block (w&1)*64 (4 DMAs)
        {
            const int kkp = wave >> 1;
            const int rb = (wave & 1) * 64;
#pragma unroll
            for (int r0 = 0; r0 < 64; r0 += 16)
                load_lds16(Vbase + (size_t)(rb + r0 + srow) * S + kv0 + kkp * 32 + scol,
                           Vs + kkp * 4096 + (rb + r0) * 32);
        }
        __syncthreads(); // DMA drained

        // S = Q K^T for both strips, sharing each bk read
        f4_t s4a[4] = {}, s4b[4] = {};
#pragma unroll
        for (int kk = 0; kk < 4; ++kk) {
#pragma unroll
            for (int j = 0; j < 4; ++j) {
                const bf8_t bk =
                    *(const bf8_t*)&Ks[kk * 2048 + (j * 16 + r16) * 32 + (q4 ^ rkey) * 8];
                s4a[j] = mfma16(aq0[kk], bk, s4a[j]);
                s4b[j] = mfma16(aq1[kk], bk, s4b[j]);
            }
        }

        // P = exp2(S*SCL) -> per-wave LDS strip (C-layout -> A-layout)
#pragma unroll
        for (int r = 0; r < 4; ++r)
#pragma unroll
            for (int j = 0; j < 4; ++j) {
                Pw[(q4 * 4 + r) * 72 + j * 16 + r16] = (bf16_t)exp2f(s4a[j][r] * SCL);
                Pw[(16 + q4 * 4 + r) * 72 + j * 16 + r16] = (bf16_t)exp2f(s4b[j][r] * SCL);
            }
        asm volatile("s_waitcnt lgkmcnt(0)" ::: "memory"); // wave-local DS drain

        bf8_t ap0[2], ap1[2];
#pragma unroll
        for (int kkp = 0; kkp < 2; ++kkp) {
            ap0[kkp] = *(const bf8_t*)&Pw[r16 * 72 + kkp * 32 + q4 * 8];
            ap1[kkp] = *(const bf8_t*)&Pw[(16 + r16) * 72 + kkp * 32 + q4 * 8];
        }

#pragma unroll
        for (int kkp = 0; kkp < 2; ++kkp) {
            lacc0 = mfma16(ap0[kkp], ones, lacc0);
            lacc1 = mfma16(ap1[kkp], ones, lacc1);
        }

        // O += P @ V, sharing each bv read between strips
#pragma unroll
        for (int t = 0; t < 8; ++t) {
#pragma unroll
            for (int kkp = 0; kkp < 2; ++kkp) {
                const bf8_t bv =
                    *(const bf8_t*)&Vs[kkp * 4096 + (t * 16 + r16) * 32 + (q4 ^ rkey) * 8];
                o0[t] = mfma16(ap0[kkp], bv, o0[t]);
                o1[t] = mfma16(ap1[kkp], bv, o1[t]);
            }
        }
    }

    f4_t inv0, inv1;
#pragma unroll
    for (int r = 0; r < 4; ++r) {
        inv0[r] = 1.0f / lacc0[r];
        inv1[r] = 1.0f / lacc1[r];
    }
#pragma unroll
    for (int t = 0; t < 8; ++t)
#pragma unroll
        for (int r = 0; r < 4; ++r) {
            O[(qrow + q4 * 4 + r) * C + h * 128 + t * 16 + r16] = (bf16_t)(o0[t][r] * inv0[r]);
            O[(qrow + 16 + q4 * 4 + r) * C + h * 128 + t * 16 + r16] =
                (bf16_t)(o1[t][r] * inv1[r]);
        }
}

extern "C" void kernel_launch(void* const* d_in, const int* in_sizes, int n_in,
                              void* d_out, int out_size, void* d_ws, size_t ws_size,
                              hipStream_t stream) {
    const float* x  = (const float*)d_in[0];
    const float* wq = (const float*)d_in[1];
    const float* wk = (const float*)d_in[2];
    const float* wv = (const float*)d_in[3];
    const float* wo = (const float*)d_in[4];

    bf16_t* ws = (bf16_t*)d_ws;
    bf16_t* xb   = ws;                         // 8,388,608
    bf16_t* Wqkv = ws + 8388608;               // 12,582,912
    bf16_t* Qb   = ws + 20971520;              // 8,388,608
    bf16_t* Kb   = ws + 29360128;              // 8,388,608
    bf16_t* Vt   = ws + 37748736;              // 8,388,608
    bf16_t* Wob  = xb;                         // aliases xb (dead after QKV gemm)
    bf16_t* At   = Wqkv;                       // aliases Wqkv (dead after QKV gemm)

    cvt_fused<<<10240, 256, 0, stream>>>(x, wq, wk, wv, xb, Wqkv);

    gemm_m97<0><<<dim3(48, 32), 256, 0, stream>>>(xb, Wqkv, Qb, Kb, Vt, 6144, 2048);

    cvt_bf16<<<2048, 256, 0, stream>>>(wo, Wob, 524288);

    flash5<<<dim3(16, 32), 256, 0, stream>>>(Qb, Kb, Vt, At);

    gemm_m97<1><<<dim3(16, 32), 256, 0, stream>>>(At, Wob, d_out, nullptr, nullptr, 2048, 2048);
}

// Round 3
// 412.500 us; speedup vs baseline: 1.0454x; 1.0454x over previous
//
#include <hip/hip_runtime.h>
#include <hip/hip_bf16.h>
#include <cstdint>
#include <cstddef>

typedef __bf16 bf16_t;
typedef __bf16 bf8_t __attribute__((ext_vector_type(8)));
typedef float f4_t __attribute__((ext_vector_type(4)));
typedef float f8_t __attribute__((ext_vector_type(8)));

#define DEV static __device__ __forceinline__

DEV f4_t mfma16(bf8_t a, bf8_t b, f4_t c) {
    return __builtin_amdgcn_mfma_f32_16x16x32_bf16(a, b, c, 0, 0, 0);
}

DEV bf8_t cvt8(f8_t v) {
    bf8_t r;
#pragma unroll
    for (int i = 0; i < 8; ++i) r[i] = (bf16_t)v[i];
    return r;
}

DEV void load_lds16(const bf16_t* g, bf16_t* l) {
    __builtin_amdgcn_global_load_lds(
        (const __attribute__((address_space(1))) uint32_t*)g,
        (__attribute__((address_space(3))) uint32_t*)l,
        16, 0, 0);
}

// Fused fp32->bf16 convert for x + wq + wk + wv in one launch.
__global__ __launch_bounds__(256) void cvt_fused(const float* __restrict__ x,
                                                 const float* __restrict__ wq,
                                                 const float* __restrict__ wk,
                                                 const float* __restrict__ wv,
                                                 bf16_t* __restrict__ xb,
                                                 bf16_t* __restrict__ wqkvb) {
    const int bid = blockIdx.x;
    const float* src;
    bf16_t* dst;
    int base;
    if (bid < 4096) {
        src = x; dst = xb; base = bid;
    } else {
        const int seg = (bid - 4096) >> 11; // 0,1,2
        src = (seg == 0) ? wq : (seg == 1) ? wk : wv;
        dst = wqkvb + (size_t)seg * 4194304;
        base = (bid - 4096) & 2047;
    }
    const size_t i = ((size_t)base * 256 + threadIdx.x) * 8;
    const f8_t v = *(const f8_t*)&src[i];
    *(bf8_t*)&dst[i] = cvt8(v);
}

__global__ __launch_bounds__(256) void cvt_bf16(const float* __restrict__ in,
                                                bf16_t* __restrict__ out, int n8) {
    const int i = blockIdx.x * 256 + threadIdx.x;
    if (i < n8) {
        const f8_t v = *(const f8_t*)&in[(size_t)i * 8];
        *(bf8_t*)&out[(size_t)i * 8] = cvt8(v);
    }
}

// ---------------------------------------------------------------------------
// QKV GEMM, 256x256 tile, BK=64 (2 ksubs of 32), 8 waves (2M x 4N), 8-phase-
// style schedule: per K-tile 4 phases x 16 MFMA, counted vmcnt(4) once per
// K-tile, raw s_barrier (no implicit vmcnt(0) drain), setprio around MFMA.
// Staging/read swizzle byte-identical to the verified m97 pattern.
// LDS 128 KiB: buf[2] x { A[2 ksub][256*32], B[2 ksub][256*32] }.
// Stage schedule (tile t): p0: A(t+1) -> other buf (4 loads); p1: B rows
// 0..127 of (t+2) -> this buf (2); p2: B rows 128..255 of (t+2) (2).
// All staged regions are barrier-separated from their last reader.
// vmcnt(4) at p3 allows only B(t+2) outstanding => A(t+1), B(t+1) landed.
// ---------------------------------------------------------------------------
DEV void stage_half(const bf16_t* X, int row0, int rb, int kt, bf16_t* bufX,
                    int wave, int srow, int scol) {
#pragma unroll
    for (int kk = 0; kk < 2; ++kk)
        load_lds16(X + (size_t)(row0 + rb + wave * 16 + srow) * 2048 + kt * 64 + kk * 32 + scol,
                   bufX + kk * 8192 + (rb + wave * 16) * 32);
}

__global__ __launch_bounds__(512, 2) void gemm256(const bf16_t* __restrict__ A,
                                                  const bf16_t* __restrict__ B,
                                                  bf16_t* __restrict__ Cq,
                                                  bf16_t* __restrict__ Ck,
                                                  bf16_t* __restrict__ Cv) {
    __shared__ bf16_t smem[65536]; // 128 KiB

    const int tid = threadIdx.x, lane = tid & 63, wave = tid >> 6;
    const int wr = wave >> 2, wc = wave & 3;
    const int q4 = lane >> 4, r16 = lane & 15;
    const int srow = lane >> 2;
    const int scol = ((lane & 3) ^ ((lane >> 3) & 3)) * 8;
    const int rkey = (r16 >> 1) & 3;

    // bijective XCD swizzle (384 blocks, 384 % 8 == 0)
    int wg = blockIdx.y * 24 + blockIdx.x;
    wg = (wg & 7) * 48 + (wg >> 3);
    const int bm0 = (wg / 24) * 256;
    const int bn0 = (wg % 24) * 256;

    f4_t acc[8][4] = {};

    // prologue: A(0),B(0) -> buf0 ; B(1) -> buf1 ; wait all but B(1)
    {
        bf16_t* b0 = smem;
        bf16_t* b1 = smem + 32768;
        stage_half(A, bm0, 0,   0, b0,          wave, srow, scol);
        stage_half(A, bm0, 128, 0, b0,          wave, srow, scol);
        stage_half(B, bn0, 0,   0, b0 + 16384,  wave, srow, scol);
        stage_half(B, bn0, 128, 0, b0 + 16384,  wave, srow, scol);
        stage_half(B, bn0, 0,   1, b1 + 16384,  wave, srow, scol);
        stage_half(B, bn0, 128, 1, b1 + 16384,  wave, srow, scol);
        asm volatile("s_waitcnt vmcnt(4)" ::: "memory");
        __builtin_amdgcn_s_barrier();
    }

    for (int t = 0; t < 32; ++t) {
        bf16_t* buf  = smem + (t & 1) * 32768;
        bf16_t* bufN = smem + ((t + 1) & 1) * 32768;

        bf8_t bq[4][2];
#pragma unroll
        for (int p = 0; p < 4; ++p) {
            if (p == 0) {
#pragma unroll
                for (int n = 0; n < 4; ++n)
#pragma unroll
                    for (int kk = 0; kk < 2; ++kk)
                        bq[n][kk] = *(const bf8_t*)&buf[16384 + kk * 8192 +
                                                       (wc * 64 + n * 16 + r16) * 32 +
                                                       (q4 ^ rkey) * 8];
            }
            bf8_t af[2][2];
#pragma unroll
            for (int i = 0; i < 2; ++i)
#pragma unroll
                for (int kk = 0; kk < 2; ++kk)
                    af[i][kk] = *(const bf8_t*)&buf[kk * 8192 +
                                                    (wr * 128 + (2 * p + i) * 16 + r16) * 32 +
                                                    (q4 ^ rkey) * 8];

            if (p == 0 && t + 1 < 32) {
                stage_half(A, bm0, 0,   t + 1, bufN, wave, srow, scol);
                stage_half(A, bm0, 128, t + 1, bufN, wave, srow, scol);
            }
            if (p == 1 && t + 2 < 32)
                stage_half(B, bn0, 0,   t + 2, buf + 16384, wave, srow, scol);
            if (p == 2 && t + 2 < 32)
                stage_half(B, bn0, 128, t + 2, buf + 16384, wave, srow, scol);

            __builtin_amdgcn_s_barrier();
            asm volatile("s_waitcnt lgkmcnt(0)" ::: "memory");
            __builtin_amdgcn_s_setprio(1);
#pragma unroll
            for (int kk = 0; kk < 2; ++kk)
#pragma unroll
                for (int i = 0; i < 2; ++i)
#pragma unroll
                    for (int n = 0; n < 4; ++n)
                        acc[2 * p + i][n] = mfma16(af[i][kk], bq[n][kk], acc[2 * p + i][n]);
            __builtin_amdgcn_s_setprio(0);
            if (p == 3) {
                if (t < 30) {
                    asm volatile("s_waitcnt vmcnt(4)" ::: "memory");
                } else {
                    asm volatile("s_waitcnt vmcnt(0)" ::: "memory");
                }
            }
            __builtin_amdgcn_s_barrier();
        }
    }

    __syncthreads(); // full drain; smem reused as per-wave repack strips

    bf16_t* strip = smem + wave * 4608; // 64 x 72 bf16 per wave
    if (bn0 < 4096) {
        bf16_t* dst = (bn0 < 2048) ? Cq : Ck;
        const int nb = (bn0 & 2047) + wc * 64;
#pragma unroll
        for (int P = 0; P < 2; ++P) {
#pragma unroll
            for (int i = 0; i < 4; ++i)
#pragma unroll
                for (int n = 0; n < 4; ++n)
#pragma unroll
                    for (int r = 0; r < 4; ++r)
                        strip[(i * 16 + q4 * 4 + r) * 72 + n * 16 + r16] =
                            (bf16_t)acc[P * 4 + i][n][r];
            asm volatile("s_waitcnt lgkmcnt(0)" ::: "memory");
#pragma unroll
            for (int it = 0; it < 8; ++it) {
                const int row = it * 8 + (lane >> 3);
                const int c = (lane & 7) * 8;
                *(bf8_t*)&dst[(size_t)(bm0 + wr * 128 + P * 64 + row) * 2048 + nb + c] =
                    *(const bf8_t*)&strip[row * 72 + c];
            }
            asm volatile("s_waitcnt lgkmcnt(0)" ::: "memory");
        }
    } else {
        const int bb = bm0 >> 11;
        const int s0 = bm0 & 2047;
#pragma unroll
        for (int P = 0; P < 2; ++P) {
#pragma unroll
            for (int i = 0; i < 4; ++i)
#pragma unroll
                for (int n = 0; n < 4; ++n)
#pragma unroll
                    for (int r = 0; r < 4; ++r)
                        strip[(n * 16 + r16) * 72 + i * 16 + q4 * 4 + r] =
                            (bf16_t)acc[P * 4 + i][n][r];
            asm volatile("s_waitcnt lgkmcnt(0)" ::: "memory");
#pragma unroll
            for (int it = 0; it < 8; ++it) {
                const int nrow = it * 8 + (lane >> 3);
                const int c = (lane & 7) * 8;
                const int dg = (bn0 - 4096) + wc * 64 + nrow;
                const int h = dg >> 7, d = dg & 127;
                *(bf8_t*)&Cv[(((size_t)(bb * 16 + h) * 128 + d) << 11) + s0 + wr * 128 + P * 64 + c] =
                    *(const bf8_t*)&strip[nrow * 72 + c];
            }
            asm volatile("s_waitcnt lgkmcnt(0)" ::: "memory");
        }
    }
}

// m97 GEMM (kept for the output projection): 128x128 tile, 2-barrier K-loop.
template <int MODE>
__global__ __launch_bounds__(256) void gemm_m97(const bf16_t* __restrict__ A,
                                                const bf16_t* __restrict__ B,
                                                void* __restrict__ C0,
                                                bf16_t* __restrict__ C1,
                                                bf16_t* __restrict__ C2,
                                                int N, int K) {
    constexpr int SMEMN = (MODE == 0) ? 128 * 136 : 8192;
    __shared__ bf16_t smem[SMEMN];
    bf16_t* As = smem;
    bf16_t* Bs = smem + 4096;

    const int tid = threadIdx.x;
    const int lane = tid & 63;
    const int wave = tid >> 6;
    const int bm0 = blockIdx.y * 128;
    const int bn0 = blockIdx.x * 128;
    const int wm = (wave >> 1) * 64;
    const int wn = (wave & 1) * 64;
    const int q4 = lane >> 4;
    const int r16 = lane & 15;

    const int srow = lane >> 2;
    const int scol = (((lane & 3) ^ ((lane >> 3) & 3))) * 8;
    const int rkey = (r16 >> 1) & 3;

    f4_t acc[4][4] = {};

    for (int k0 = 0; k0 < K; k0 += 32) {
        __syncthreads();
        load_lds16(A + (size_t)(bm0 + wave * 16 + srow) * K + k0 + scol, As + wave * 16 * 32);
        load_lds16(A + (size_t)(bm0 + 64 + wave * 16 + srow) * K + k0 + scol,
                   As + (64 + wave * 16) * 32);
        load_lds16(B + (size_t)(bn0 + wave * 16 + srow) * K + k0 + scol, Bs + wave * 16 * 32);
        load_lds16(B + (size_t)(bn0 + 64 + wave * 16 + srow) * K + k0 + scol,
                   Bs + (64 + wave * 16) * 32);
        __syncthreads();

        bf8_t af[4], bfr[4];
#pragma unroll
        for (int i = 0; i < 4; ++i)
            af[i] = *(const bf8_t*)&As[(wm + i * 16 + r16) * 32 + (q4 ^ rkey) * 8];
#pragma unroll
        for (int j = 0; j < 4; ++j)
            bfr[j] = *(const bf8_t*)&Bs[(wn + j * 16 + r16) * 32 + (q4 ^ rkey) * 8];
#pragma unroll
        for (int i = 0; i < 4; ++i)
#pragma unroll
            for (int j = 0; j < 4; ++j)
                acc[i][j] = mfma16(af[i], bfr[j], acc[i][j]);
    }

    if (MODE == 1) {
        float* C = (float*)C0;
#pragma unroll
        for (int i = 0; i < 4; ++i)
#pragma unroll
            for (int j = 0; j < 4; ++j)
#pragma unroll
                for (int r = 0; r < 4; ++r) {
                    const int m = bm0 + wm + i * 16 + q4 * 4 + r;
                    const int n = bn0 + wn + j * 16 + r16;
                    C[(size_t)m * 2048 + n] = acc[i][j][r];
                }
        return;
    }

    __syncthreads();
    if (bn0 < 4096) {
        bf16_t* dst = (bn0 < 2048) ? (bf16_t*)C0 : C1;
        const int nbase = bn0 & 2047;
#pragma unroll
        for (int i = 0; i < 4; ++i)
#pragma unroll
            for (int j = 0; j < 4; ++j)
#pragma unroll
                for (int r = 0; r < 4; ++r)
                    smem[(wm + i * 16 + q4 * 4 + r) * 136 + wn + j * 16 + r16] =
                        (bf16_t)acc[i][j][r];
        __syncthreads();
#pragma unroll
        for (int it = 0; it < 8; ++it) {
            const int idx = it * 256 + tid;
            const int m = idx >> 4;
            const int nc = (idx & 15) * 8;
            *(bf8_t*)&dst[(size_t)(bm0 + m) * 2048 + nbase + nc] =
                *(const bf8_t*)&smem[m * 136 + nc];
        }
    } else {
#pragma unroll
        for (int i = 0; i < 4; ++i)
#pragma unroll
            for (int j = 0; j < 4; ++j)
#pragma unroll
                for (int r = 0; r < 4; ++r)
                    smem[(wn + j * 16 + r16) * 136 + wm + i * 16 + q4 * 4 + r] =
                        (bf16_t)acc[i][j][r];
        __syncthreads();
        const int bb = bm0 >> 11;
        const int s0 = bm0 & 2047;
        const int nh0 = bn0 - 4096;
#pragma unroll
        for (int it = 0; it < 8; ++it) {
            const int idx = it * 256 + tid;
            const int n = idx >> 4;
            const int mc = (idx & 15) * 8;
            const bf8_t v = *(const bf8_t*)&smem[n * 136 + mc];
            const int dg = nh0 + n;
            const int h = dg >> 7, d = dg & 127;
            *(bf8_t*)&C2[(((size_t)(bb * 16 + h) * 128 + d) << 11) + s0 + mc] = v;
        }
    }
}

// Flash v5: 4 waves x 32 q rows (two 16-row strips/wave); swizzled K/V LDS;
// shuffle-free softmax (no max, ones-MFMA row sums).
__global__ __launch_bounds__(256) void flash5(const bf16_t* __restrict__ Q,
                                              const bf16_t* __restrict__ K,
                                              const bf16_t* __restrict__ VT,
                                              bf16_t* __restrict__ O) {
    constexpr int S = 2048, C = 2048;
    constexpr float SCL = 0.08838834764831845f * 1.4426950408889634f;
    __shared__ bf16_t Ks[4 * 64 * 32];
    __shared__ bf16_t Vs[2 * 128 * 32];
    __shared__ bf16_t Ps[4][32 * 72];

    const int tid = threadIdx.x, lane = tid & 63, wave = tid >> 6;
    const int q4 = lane >> 4, r16 = lane & 15;
    const int bh = blockIdx.y, b = bh >> 4, h = bh & 15;
    const int q0 = blockIdx.x * 128 + wave * 32;

    const size_t qrow = (size_t)b * S + q0;
    const bf16_t* Qp0 = Q + (qrow + r16) * C + h * 128;
    const bf16_t* Qp1 = Q + (qrow + 16 + r16) * C + h * 128;
    const bf16_t* Kbase = K + (size_t)b * S * C + h * 128;
    const bf16_t* Vbase = VT + (size_t)bh * 128 * S;
    bf16_t* Pw = &Ps[wave][0];

    const int srow = lane >> 2;
    const int scol = (((lane & 3) ^ ((lane >> 3) & 3))) * 8;
    const int rkey = (r16 >> 1) & 3;

    bf8_t aq0[4], aq1[4];
#pragma unroll
    for (int kk = 0; kk < 4; ++kk) {
        aq0[kk] = *(const bf8_t*)&Qp0[kk * 32 + q4 * 8];
        aq1[kk] = *(const bf8_t*)&Qp1[kk * 32 + q4 * 8];
    }

    bf8_t ones;
#pragma unroll
    for (int i = 0; i < 8; ++i) ones[i] = (bf16_t)1.0f;

    f4_t o0[8] = {}, o1[8] = {};
    f4_t lacc0 = {}, lacc1 = {};

    for (int kv0 = 0; kv0 < S; kv0 += 64) {
        __syncthreads();
#pragma unroll
        for (int r0 = 0; r0 < 64; r0 += 16)
            load_lds16(Kbase + (size_t)(kv0 + r0 + srow) * C + wave * 32 + scol,
                       Ks + wave * 2048 + r0 * 32);
        {
            const int kkp = wave >> 1;
            const int rb = (wave & 1) * 64;
#pragma unroll
            for (int r0 = 0; r0 < 64; r0 += 16)
                load_lds16(Vbase + (size_t)(rb + r0 + srow) * S + kv0 + kkp * 32 + scol,
                           Vs + kkp * 4096 + (rb + r0) * 32);
        }
        __syncthreads();

        f4_t s4a[4] = {}, s4b[4] = {};
#pragma unroll
        for (int kk = 0; kk < 4; ++kk) {
#pragma unroll
            for (int j = 0; j < 4; ++j) {
                const bf8_t bk =
                    *(const bf8_t*)&Ks[kk * 2048 + (j * 16 + r16) * 32 + (q4 ^ rkey) * 8];
                s4a[j] = mfma16(aq0[kk], bk, s4a[j]);
                s4b[j] = mfma16(aq1[kk], bk, s4b[j]);
            }
        }

#pragma unroll
        for (int r = 0; r < 4; ++r)
#pragma unroll
            for (int j = 0; j < 4; ++j) {
                Pw[(q4 * 4 + r) * 72 + j * 16 + r16] = (bf16_t)exp2f(s4a[j][r] * SCL);
                Pw[(16 + q4 * 4 + r) * 72 + j * 16 + r16] = (bf16_t)exp2f(s4b[j][r] * SCL);
            }
        asm volatile("s_waitcnt lgkmcnt(0)" ::: "memory");

        bf8_t ap0[2], ap1[2];
#pragma unroll
        for (int kkp = 0; kkp < 2; ++kkp) {
            ap0[kkp] = *(const bf8_t*)&Pw[r16 * 72 + kkp * 32 + q4 * 8];
            ap1[kkp] = *(const bf8_t*)&Pw[(16 + r16) * 72 + kkp * 32 + q4 * 8];
        }

#pragma unroll
        for (int kkp = 0; kkp < 2; ++kkp) {
            lacc0 = mfma16(ap0[kkp], ones, lacc0);
            lacc1 = mfma16(ap1[kkp], ones, lacc1);
        }

#pragma unroll
        for (int t = 0; t < 8; ++t) {
#pragma unroll
            for (int kkp = 0; kkp < 2; ++kkp) {
                const bf8_t bv =
                    *(const bf8_t*)&Vs[kkp * 4096 + (t * 16 + r16) * 32 + (q4 ^ rkey) * 8];
                o0[t] = mfma16(ap0[kkp], bv, o0[t]);
                o1[t] = mfma16(ap1[kkp], bv, o1[t]);
            }
        }
    }

    f4_t inv0, inv1;
#pragma unroll
    for (int r = 0; r < 4; ++r) {
        inv0[r] = 1.0f / lacc0[r];
        inv1[r] = 1.0f / lacc1[r];
    }
#pragma unroll
    for (int t = 0; t < 8; ++t)
#pragma unroll
        for (int r = 0; r < 4; ++r) {
            O[(qrow + q4 * 4 + r) * C + h * 128 + t * 16 + r16] = (bf16_t)(o0[t][r] * inv0[r]);
            O[(qrow + 16 + q4 * 4 + r) * C + h * 128 + t * 16 + r16] =
                (bf16_t)(o1[t][r] * inv1[r]);
        }
}

extern "C" void kernel_launch(void* const* d_in, const int* in_sizes, int n_in,
                              void* d_out, int out_size, void* d_ws, size_t ws_size,
                              hipStream_t stream) {
    const float* x  = (const float*)d_in[0];
    const float* wq = (const float*)d_in[1];
    const float* wk = (const float*)d_in[2];
    const float* wv = (const float*)d_in[3];
    const float* wo = (const float*)d_in[4];

    bf16_t* ws = (bf16_t*)d_ws;
    bf16_t* xb   = ws;                         // 8,388,608
    bf16_t* Wqkv = ws + 8388608;               // 12,582,912
    bf16_t* Qb   = ws + 20971520;              // 8,388,608
    bf16_t* Kb   = ws + 29360128;              // 8,388,608
    bf16_t* Vt   = ws + 37748736;              // 8,388,608
    bf16_t* Wob  = xb;                         // aliases xb (dead after QKV gemm)
    bf16_t* At   = Wqkv;                       // aliases Wqkv (dead after QKV gemm)

    cvt_fused<<<10240, 256, 0, stream>>>(x, wq, wk, wv, xb, Wqkv);

    gemm256<<<dim3(24, 16), 512, 0, stream>>>(xb, Wqkv, Qb, Kb, Vt);

    cvt_bf16<<<2048, 256, 0, stream>>>(wo, Wob, 524288);

    flash5<<<dim3(16, 32), 256, 0, stream>>>(Qb, Kb, Vt, At);

    gemm_m97<1><<<dim3(16, 32), 256, 0, stream>>>(At, Wob, d_out, nullptr, nullptr, 2048, 2048);
}

// Round 4
// 409.805 us; speedup vs baseline: 1.0523x; 1.0066x over previous
//
#include <hip/hip_runtime.h>
#include <hip/hip_bf16.h>
#include <cstdint>
#include <cstddef>

typedef __bf16 bf16_t;
typedef __bf16 bf8_t __attribute__((ext_vector_type(8)));
typedef float f4_t __attribute__((ext_vector_type(4)));
typedef float f8_t __attribute__((ext_vector_type(8)));

#define DEV static __device__ __forceinline__

DEV f4_t mfma16(bf8_t a, bf8_t b, f4_t c) {
    return __builtin_amdgcn_mfma_f32_16x16x32_bf16(a, b, c, 0, 0, 0);
}

DEV bf8_t cvt8(f8_t v) {
    bf8_t r;
#pragma unroll
    for (int i = 0; i < 8; ++i) r[i] = (bf16_t)v[i];
    return r;
}

DEV void load_lds16(const bf16_t* g, bf16_t* l) {
    __builtin_amdgcn_global_load_lds(
        (const __attribute__((address_space(1))) uint32_t*)g,
        (__attribute__((address_space(3))) uint32_t*)l,
        16, 0, 0);
}

// Fused fp32->bf16 convert for x + wq + wk + wv in one launch.
__global__ __launch_bounds__(256) void cvt_fused(const float* __restrict__ x,
                                                 const float* __restrict__ wq,
                                                 const float* __restrict__ wk,
                                                 const float* __restrict__ wv,
                                                 bf16_t* __restrict__ xb,
                                                 bf16_t* __restrict__ wqkvb) {
    const int bid = blockIdx.x;
    const float* src;
    bf16_t* dst;
    int base;
    if (bid < 4096) {
        src = x; dst = xb; base = bid;
    } else {
        const int seg = (bid - 4096) >> 11; // 0,1,2
        src = (seg == 0) ? wq : (seg == 1) ? wk : wv;
        dst = wqkvb + (size_t)seg * 4194304;
        base = (bid - 4096) & 2047;
    }
    const size_t i = ((size_t)base * 256 + threadIdx.x) * 8;
    const f8_t v = *(const f8_t*)&src[i];
    *(bf8_t*)&dst[i] = cvt8(v);
}

__global__ __launch_bounds__(256) void cvt_bf16(const float* __restrict__ in,
                                                bf16_t* __restrict__ out, int n8) {
    const int i = blockIdx.x * 256 + threadIdx.x;
    if (i < n8) {
        const f8_t v = *(const f8_t*)&in[(size_t)i * 8];
        *(bf8_t*)&out[(size_t)i * 8] = cvt8(v);
    }
}

// ---------------------------------------------------------------------------
// QKV GEMM, 128x256 tile, BK=64 (2 ksubs of 32), 8 waves (2M x 4N, 64x64 per
// wave). Grid 32x24 = 768 blocks = exactly 3 full rounds on 256 CUs (fixes
// the 1.5-round quantization of the 256x256 version). Per K-tile: 2 phases x
// 16 MFMA, counted vmcnt(4) once per K-tile (never 0 in steady state), raw
// s_barrier, setprio around MFMA. Staging/read swizzle identical to the
// verified m97/round-2 pattern. LDS 96 KiB: buf[2] x { A[2kk][128*32],
// B[2kk][256*32] }. Stage schedule (tile t): p0: A(t+1)->other buf (2 loads/
// wave); p1: B(t+2)->this buf's B region (4 loads/wave; that region's last
// reader was p0, barrier-separated). vmcnt(4) at p1-end leaves only B(t+2)
// outstanding => A(t+1),B(t+1) landed (vmcnt retires in issue order).
// ---------------------------------------------------------------------------
__global__ __launch_bounds__(512, 2) void gemm_qkv(const bf16_t* __restrict__ A,
                                                   const bf16_t* __restrict__ B,
                                                   bf16_t* __restrict__ Cq,
                                                   bf16_t* __restrict__ Ck,
                                                   bf16_t* __restrict__ Cv) {
    __shared__ bf16_t smem[49152]; // 96 KiB: 2 bufs x (A 8192 + B 16384 elems)

    const int tid = threadIdx.x, lane = tid & 63, wave = tid >> 6;
    const int wr = wave >> 2, wc = wave & 3;
    const int q4 = lane >> 4, r16 = lane & 15;
    const int srow = lane >> 2;
    const int scol = ((lane & 3) ^ ((lane >> 3) & 3)) * 8;
    const int rkey = (r16 >> 1) & 3;

    // bijective XCD-chunked swizzle (768 % 8 == 0)
    int wg = blockIdx.y * 24 + blockIdx.x;
    wg = (wg & 7) * 96 + (wg >> 3);
    const int bm0 = (wg / 24) * 128;
    const int bn0 = (wg % 24) * 256;

    f4_t acc[4][4] = {};

    auto stageA = [&](int kt, bf16_t* buf) {
#pragma unroll
        for (int kk = 0; kk < 2; ++kk)
            load_lds16(A + (size_t)(bm0 + wave * 16 + srow) * 2048 + kt * 64 + kk * 32 + scol,
                       buf + kk * 4096 + wave * 16 * 32);
    };
    auto stageB = [&](int kt, bf16_t* buf, int rb) {
#pragma unroll
        for (int kk = 0; kk < 2; ++kk)
            load_lds16(B + (size_t)(bn0 + rb + wave * 16 + srow) * 2048 + kt * 64 + kk * 32 + scol,
                       buf + 8192 + kk * 8192 + (rb + wave * 16) * 32);
    };

    // prologue: A(0),B(0) -> buf0 ; B(1) -> buf1 ; wait all but B(1)
    {
        bf16_t* b0 = smem;
        bf16_t* b1 = smem + 24576;
        stageA(0, b0);
        stageB(0, b0, 0);
        stageB(0, b0, 128);
        stageB(1, b1, 0);
        stageB(1, b1, 128);
        asm volatile("s_waitcnt vmcnt(4)" ::: "memory");
        __builtin_amdgcn_s_barrier();
    }

    for (int t = 0; t < 32; ++t) {
        bf16_t* buf  = smem + (t & 1) * 24576;
        bf16_t* bufN = smem + ((t + 1) & 1) * 24576;

        // all B fragments for this K-tile (held across both phases)
        bf8_t bq[4][2];
#pragma unroll
        for (int n = 0; n < 4; ++n)
#pragma unroll
            for (int kk = 0; kk < 2; ++kk)
                bq[n][kk] = *(const bf8_t*)&buf[8192 + kk * 8192 +
                                                (wc * 64 + n * 16 + r16) * 32 +
                                                (q4 ^ rkey) * 8];

        // ---- phase 0: i = 0,1 ----
        {
            bf8_t af[2][2];
#pragma unroll
            for (int i = 0; i < 2; ++i)
#pragma unroll
                for (int kk = 0; kk < 2; ++kk)
                    af[i][kk] = *(const bf8_t*)&buf[kk * 4096 +
                                                    (wr * 64 + i * 16 + r16) * 32 +
                                                    (q4 ^ rkey) * 8];
            if (t + 1 < 32) stageA(t + 1, bufN);
            __builtin_amdgcn_s_barrier();
            asm volatile("s_waitcnt lgkmcnt(0)" ::: "memory");
            __builtin_amdgcn_s_setprio(1);
#pragma unroll
            for (int kk = 0; kk < 2; ++kk)
#pragma unroll
                for (int i = 0; i < 2; ++i)
#pragma unroll
                    for (int n = 0; n < 4; ++n)
                        acc[i][n] = mfma16(af[i][kk], bq[n][kk], acc[i][n]);
            __builtin_amdgcn_s_setprio(0);
            __builtin_amdgcn_s_barrier();
        }

        // ---- phase 1: i = 2,3 ----
        {
            bf8_t af[2][2];
#pragma unroll
            for (int i = 0; i < 2; ++i)
#pragma unroll
                for (int kk = 0; kk < 2; ++kk)
                    af[i][kk] = *(const bf8_t*)&buf[kk * 4096 +
                                                    (wr * 64 + (2 + i) * 16 + r16) * 32 +
                                                    (q4 ^ rkey) * 8];
            if (t + 2 < 32) {
                stageB(t + 2, buf, 0);
                stageB(t + 2, buf, 128);
            }
            __builtin_amdgcn_s_barrier();
            asm volatile("s_waitcnt lgkmcnt(0)" ::: "memory");
            __builtin_amdgcn_s_setprio(1);
#pragma unroll
            for (int kk = 0; kk < 2; ++kk)
#pragma unroll
                for (int i = 0; i < 2; ++i)
#pragma unroll
                    for (int n = 0; n < 4; ++n)
                        acc[2 + i][n] = mfma16(af[i][kk], bq[n][kk], acc[2 + i][n]);
            __builtin_amdgcn_s_setprio(0);
            if (t < 30) {
                asm volatile("s_waitcnt vmcnt(4)" ::: "memory");
            } else {
                asm volatile("s_waitcnt vmcnt(0)" ::: "memory");
            }
            __builtin_amdgcn_s_barrier();
        }
    }

    __syncthreads(); // full drain; smem reused as per-wave repack strips

    bf16_t* strip = smem + wave * 4608; // 64 x 72 bf16 per wave
    if (bn0 < 4096) {
        bf16_t* dst = (bn0 < 2048) ? Cq : Ck;
        const int nb = (bn0 & 2047) + wc * 64;
#pragma unroll
        for (int i = 0; i < 4; ++i)
#pragma unroll
            for (int n = 0; n < 4; ++n)
#pragma unroll
                for (int r = 0; r < 4; ++r)
                    strip[(i * 16 + q4 * 4 + r) * 72 + n * 16 + r16] =
                        (bf16_t)acc[i][n][r];
        asm volatile("s_waitcnt lgkmcnt(0)" ::: "memory");
#pragma unroll
        for (int it = 0; it < 8; ++it) {
            const int row = it * 8 + (lane >> 3);
            const int c = (lane & 7) * 8;
            *(bf8_t*)&dst[(size_t)(bm0 + wr * 64 + row) * 2048 + nb + c] =
                *(const bf8_t*)&strip[row * 72 + c];
        }
    } else {
        // V: transpose in strip, stores to Vt [bh][d][s]
        const int bb = bm0 >> 11;
        const int s0 = (bm0 & 2047) + wr * 64;
#pragma unroll
        for (int i = 0; i < 4; ++i)
#pragma unroll
            for (int n = 0; n < 4; ++n)
#pragma unroll
                for (int r = 0; r < 4; ++r)
                    strip[(n * 16 + r16) * 72 + i * 16 + q4 * 4 + r] =
                        (bf16_t)acc[i][n][r];
        asm volatile("s_waitcnt lgkmcnt(0)" ::: "memory");
#pragma unroll
        for (int it = 0; it < 8; ++it) {
            const int nrow = it * 8 + (lane >> 3);
            const int c = (lane & 7) * 8;
            const int dg = (bn0 - 4096) + wc * 64 + nrow;
            const int h = dg >> 7, d = dg & 127;
            *(bf8_t*)&Cv[(((size_t)(bb * 16 + h) * 128 + d) << 11) + s0 + c] =
                *(const bf8_t*)&strip[nrow * 72 + c];
        }
    }
}

// m97 GEMM (output projection): 128x128 tile, 2-barrier K-loop.
template <int MODE>
__global__ __launch_bounds__(256) void gemm_m97(const bf16_t* __restrict__ A,
                                                const bf16_t* __restrict__ B,
                                                void* __restrict__ C0,
                                                bf16_t* __restrict__ C1,
                                                bf16_t* __restrict__ C2,
                                                int N, int K) {
    constexpr int SMEMN = (MODE == 0) ? 128 * 136 : 8192;
    __shared__ bf16_t smem[SMEMN];
    bf16_t* As = smem;
    bf16_t* Bs = smem + 4096;

    const int tid = threadIdx.x;
    const int lane = tid & 63;
    const int wave = tid >> 6;
    const int bm0 = blockIdx.y * 128;
    const int bn0 = blockIdx.x * 128;
    const int wm = (wave >> 1) * 64;
    const int wn = (wave & 1) * 64;
    const int q4 = lane >> 4;
    const int r16 = lane & 15;

    const int srow = lane >> 2;
    const int scol = (((lane & 3) ^ ((lane >> 3) & 3))) * 8;
    const int rkey = (r16 >> 1) & 3;

    f4_t acc[4][4] = {};

    for (int k0 = 0; k0 < K; k0 += 32) {
        __syncthreads();
        load_lds16(A + (size_t)(bm0 + wave * 16 + srow) * K + k0 + scol, As + wave * 16 * 32);
        load_lds16(A + (size_t)(bm0 + 64 + wave * 16 + srow) * K + k0 + scol,
                   As + (64 + wave * 16) * 32);
        load_lds16(B + (size_t)(bn0 + wave * 16 + srow) * K + k0 + scol, Bs + wave * 16 * 32);
        load_lds16(B + (size_t)(bn0 + 64 + wave * 16 + srow) * K + k0 + scol,
                   Bs + (64 + wave * 16) * 32);
        __syncthreads();

        bf8_t af[4], bfr[4];
#pragma unroll
        for (int i = 0; i < 4; ++i)
            af[i] = *(const bf8_t*)&As[(wm + i * 16 + r16) * 32 + (q4 ^ rkey) * 8];
#pragma unroll
        for (int j = 0; j < 4; ++j)
            bfr[j] = *(const bf8_t*)&Bs[(wn + j * 16 + r16) * 32 + (q4 ^ rkey) * 8];
#pragma unroll
        for (int i = 0; i < 4; ++i)
#pragma unroll
            for (int j = 0; j < 4; ++j)
                acc[i][j] = mfma16(af[i], bfr[j], acc[i][j]);
    }

    if (MODE == 1) {
        float* C = (float*)C0;
#pragma unroll
        for (int i = 0; i < 4; ++i)
#pragma unroll
            for (int j = 0; j < 4; ++j)
#pragma unroll
                for (int r = 0; r < 4; ++r) {
                    const int m = bm0 + wm + i * 16 + q4 * 4 + r;
                    const int n = bn0 + wn + j * 16 + r16;
                    C[(size_t)m * 2048 + n] = acc[i][j][r];
                }
        return;
    }

    __syncthreads();
    if (bn0 < 4096) {
        bf16_t* dst = (bn0 < 2048) ? (bf16_t*)C0 : C1;
        const int nbase = bn0 & 2047;
#pragma unroll
        for (int i = 0; i < 4; ++i)
#pragma unroll
            for (int j = 0; j < 4; ++j)
#pragma unroll
                for (int r = 0; r < 4; ++r)
                    smem[(wm + i * 16 + q4 * 4 + r) * 136 + wn + j * 16 + r16] =
                        (bf16_t)acc[i][j][r];
        __syncthreads();
#pragma unroll
        for (int it = 0; it < 8; ++it) {
            const int idx = it * 256 + tid;
            const int m = idx >> 4;
            const int nc = (idx & 15) * 8;
            *(bf8_t*)&dst[(size_t)(bm0 + m) * 2048 + nbase + nc] =
                *(const bf8_t*)&smem[m * 136 + nc];
        }
    } else {
#pragma unroll
        for (int i = 0; i < 4; ++i)
#pragma unroll
            for (int j = 0; j < 4; ++j)
#pragma unroll
                for (int r = 0; r < 4; ++r)
                    smem[(wn + j * 16 + r16) * 136 + wm + i * 16 + q4 * 4 + r] =
                        (bf16_t)acc[i][j][r];
        __syncthreads();
        const int bb = bm0 >> 11;
        const int s0 = bm0 & 2047;
        const int nh0 = bn0 - 4096;
#pragma unroll
        for (int it = 0; it < 8; ++it) {
            const int idx = it * 256 + tid;
            const int n = idx >> 4;
            const int mc = (idx & 15) * 8;
            const bf8_t v = *(const bf8_t*)&smem[n * 136 + mc];
            const int dg = nh0 + n;
            const int h = dg >> 7, d = dg & 127;
            *(bf8_t*)&C2[(((size_t)(bb * 16 + h) * 128 + d) << 11) + s0 + mc] = v;
        }
    }
}

// Flash v5: 4 waves x 32 q rows (two 16-row strips/wave); swizzled K/V LDS;
// shuffle-free softmax (no max, ones-MFMA row sums).
__global__ __launch_bounds__(256) void flash5(const bf16_t* __restrict__ Q,
                                              const bf16_t* __restrict__ K,
                                              const bf16_t* __restrict__ VT,
                                              bf16_t* __restrict__ O) {
    constexpr int S = 2048, C = 2048;
    constexpr float SCL = 0.08838834764831845f * 1.4426950408889634f;
    __shared__ bf16_t Ks[4 * 64 * 32];
    __shared__ bf16_t Vs[2 * 128 * 32];
    __shared__ bf16_t Ps[4][32 * 72];

    const int tid = threadIdx.x, lane = tid & 63, wave = tid >> 6;
    const int q4 = lane >> 4, r16 = lane & 15;
    const int bh = blockIdx.y, b = bh >> 4, h = bh & 15;
    const int q0 = blockIdx.x * 128 + wave * 32;

    const size_t qrow = (size_t)b * S + q0;
    const bf16_t* Qp0 = Q + (qrow + r16) * C + h * 128;
    const bf16_t* Qp1 = Q + (qrow + 16 + r16) * C + h * 128;
    const bf16_t* Kbase = K + (size_t)b * S * C + h * 128;
    const bf16_t* Vbase = VT + (size_t)bh * 128 * S;
    bf16_t* Pw = &Ps[wave][0];

    const int srow = lane >> 2;
    const int scol = (((lane & 3) ^ ((lane >> 3) & 3))) * 8;
    const int rkey = (r16 >> 1) & 3;

    bf8_t aq0[4], aq1[4];
#pragma unroll
    for (int kk = 0; kk < 4; ++kk) {
        aq0[kk] = *(const bf8_t*)&Qp0[kk * 32 + q4 * 8];
        aq1[kk] = *(const bf8_t*)&Qp1[kk * 32 + q4 * 8];
    }

    bf8_t ones;
#pragma unroll
    for (int i = 0; i < 8; ++i) ones[i] = (bf16_t)1.0f;

    f4_t o0[8] = {}, o1[8] = {};
    f4_t lacc0 = {}, lacc1 = {};

    for (int kv0 = 0; kv0 < S; kv0 += 64) {
        __syncthreads();
#pragma unroll
        for (int r0 = 0; r0 < 64; r0 += 16)
            load_lds16(Kbase + (size_t)(kv0 + r0 + srow) * C + wave * 32 + scol,
                       Ks + wave * 2048 + r0 * 32);
        {
            const int kkp = wave >> 1;
            const int rb = (wave & 1) * 64;
#pragma unroll
            for (int r0 = 0; r0 < 64; r0 += 16)
                load_lds16(Vbase + (size_t)(rb + r0 + srow) * S + kv0 + kkp * 32 + scol,
                           Vs + kkp * 4096 + (rb + r0) * 32);
        }
        __syncthreads();

        f4_t s4a[4] = {}, s4b[4] = {};
#pragma unroll
        for (int kk = 0; kk < 4; ++kk) {
#pragma unroll
            for (int j = 0; j < 4; ++j) {
                const bf8_t bk =
                    *(const bf8_t*)&Ks[kk * 2048 + (j * 16 + r16) * 32 + (q4 ^ rkey) * 8];
                s4a[j] = mfma16(aq0[kk], bk, s4a[j]);
                s4b[j] = mfma16(aq1[kk], bk, s4b[j]);
            }
        }

#pragma unroll
        for (int r = 0; r < 4; ++r)
#pragma unroll
            for (int j = 0; j < 4; ++j) {
                Pw[(q4 * 4 + r) * 72 + j * 16 + r16] = (bf16_t)exp2f(s4a[j][r] * SCL);
                Pw[(16 + q4 * 4 + r) * 72 + j * 16 + r16] = (bf16_t)exp2f(s4b[j][r] * SCL);
            }
        asm volatile("s_waitcnt lgkmcnt(0)" ::: "memory");

        bf8_t ap0[2], ap1[2];
#pragma unroll
        for (int kkp = 0; kkp < 2; ++kkp) {
            ap0[kkp] = *(const bf8_t*)&Pw[r16 * 72 + kkp * 32 + q4 * 8];
            ap1[kkp] = *(const bf8_t*)&Pw[(16 + r16) * 72 + kkp * 32 + q4 * 8];
        }

#pragma unroll
        for (int kkp = 0; kkp < 2; ++kkp) {
            lacc0 = mfma16(ap0[kkp], ones, lacc0);
            lacc1 = mfma16(ap1[kkp], ones, lacc1);
        }

#pragma unroll
        for (int t = 0; t < 8; ++t) {
#pragma unroll
            for (int kkp = 0; kkp < 2; ++kkp) {
                const bf8_t bv =
                    *(const bf8_t*)&Vs[kkp * 4096 + (t * 16 + r16) * 32 + (q4 ^ rkey) * 8];
                o0[t] = mfma16(ap0[kkp], bv, o0[t]);
                o1[t] = mfma16(ap1[kkp], bv, o1[t]);
            }
        }
    }

    f4_t inv0, inv1;
#pragma unroll
    for (int r = 0; r < 4; ++r) {
        inv0[r] = 1.0f / lacc0[r];
        inv1[r] = 1.0f / lacc1[r];
    }
#pragma unroll
    for (int t = 0; t < 8; ++t)
#pragma unroll
        for (int r = 0; r < 4; ++r) {
            O[(qrow + q4 * 4 + r) * C + h * 128 + t * 16 + r16] = (bf16_t)(o0[t][r] * inv0[r]);
            O[(qrow + 16 + q4 * 4 + r) * C + h * 128 + t * 16 + r16] =
                (bf16_t)(o1[t][r] * inv1[r]);
        }
}

extern "C" void kernel_launch(void* const* d_in, const int* in_sizes, int n_in,
                              void* d_out, int out_size, void* d_ws, size_t ws_size,
                              hipStream_t stream) {
    const float* x  = (const float*)d_in[0];
    const float* wq = (const float*)d_in[1];
    const float* wk = (const float*)d_in[2];
    const float* wv = (const float*)d_in[3];
    const float* wo = (const float*)d_in[4];

    bf16_t* ws = (bf16_t*)d_ws;
    bf16_t* xb   = ws;                         // 8,388,608
    bf16_t* Wqkv = ws + 8388608;               // 12,582,912
    bf16_t* Qb   = ws + 20971520;              // 8,388,608
    bf16_t* Kb   = ws + 29360128;              // 8,388,608
    bf16_t* Vt   = ws + 37748736;              // 8,388,608
    bf16_t* Wob  = xb;                         // aliases xb (dead after QKV gemm)
    bf16_t* At   = Wqkv;                       // aliases Wqkv (dead after QKV gemm)

    cvt_fused<<<10240, 256, 0, stream>>>(x, wq, wk, wv, xb, Wqkv);

    gemm_qkv<<<dim3(24, 32), 512, 0, stream>>>(xb, Wqkv, Qb, Kb, Vt);

    cvt_bf16<<<2048, 256, 0, stream>>>(wo, Wob, 524288);

    flash5<<<dim3(16, 32), 256, 0, stream>>>(Qb, Kb, Vt, At);

    gemm_m97<1><<<dim3(16, 32), 256, 0, stream>>>(At, Wob, d_out, nullptr, nullptr, 2048, 2048);
}